// Round 8
// baseline (182.625 us; speedup 1.0000x reference)
//
#include <hip/hip_runtime.h>

// 3x3 SAME conv + bias + ReLU, N=32, Cin=Cout=256, H=W=56, fp32 in/out.
// v8: implicit-GEMM bf16 MFMA with counted-vmcnt pipeline (T3+T4+T5):
//  - x pre-transformed to NHWC bf16 (x_t[pix][ci]) once per launch.
//  - A (weights) + B (x_t) staged via async global_load_lds w=16,
//    pre-swizzled per-lane GLOBAL source, linear LDS dest, 64B rows,
//    slot XOR = (row>>1)&3.
//  - BK=32, 4 LDS buffers (16KB each half), prefetch depth 3,
//    s_waitcnt vmcnt(8) fused with s_barrier - never vmcnt(0) in loop.
//  - BM=128co x BN=128px, 4 waves, wave tile 64x64 (m4,n4), 72 K-steps,
//    16 MFMA per step wrapped in setprio(1)/(0).

#define GLOBAL_AS __attribute__((address_space(1)))
#define LDS_AS __attribute__((address_space(3)))

typedef __attribute__((ext_vector_type(8))) short short8;
typedef __attribute__((ext_vector_type(4))) float f32x4;
typedef __attribute__((ext_vector_type(4))) unsigned int u32x4;

#define CIN   256
#define HWS   3136        // 56*56
#define PTOT  100352      // 32*3136
#define KTOT  2304        // CIN*9
#define WROWB 4608        // KTOT*2 bytes per weight row
#define ZPOFF 1179648     // 512B zero page
#define XTOFF 1310720     // x_t: PTOT*512 bytes
#define WSNEED (XTOFF + (size_t)PTOT * 512)

__device__ __forceinline__ unsigned short f2bf(float f) {
  unsigned u = __builtin_bit_cast(unsigned, f);
  return (unsigned short)((u + 0x7fffu + ((u >> 16) & 1u)) >> 16);  // RNE
}

// Weights OIHW fp32 -> bf16 [co][tap*256+ci]; also zero the zero-page.
__global__ void wcvt_kernel(const float* __restrict__ w, unsigned char* __restrict__ ws) {
  if (blockIdx.x == 0 && threadIdx.x < 128)
    ((unsigned*)(ws + ZPOFF))[threadIdx.x] = 0u;
  int o = blockIdx.x * 256 + threadIdx.x;
  int co = o / KTOT;
  int rr = o - co * KTOT;
  int tap = rr >> 8;
  int ci = rr & 255;
  ((unsigned short*)ws)[o] = f2bf(w[co * KTOT + ci * 9 + tap]);
}

// x NCHW fp32 -> x_t [pix_global][256ci] bf16 (NHWC), via LDS transpose.
__global__ __launch_bounds__(256) void xcvt_kernel(const float* __restrict__ x,
                                                   unsigned char* __restrict__ ws) {
  __shared__ float lt[64 * 257];
  const int pg0 = blockIdx.x * 64;       // 64-px tile, never crosses images
  const int n   = pg0 / HWS;
  const int pi0 = pg0 - n * HWS;
  const int t   = threadIdx.x;
  {
    const int px = t & 63;
    const int cg = t >> 6;               // 0..3 (wave-uniform)
    const float* xb = x + ((size_t)n * 256) * HWS + pi0 + px;
#pragma unroll 8
    for (int i = 0; i < 64; ++i) {
      const int c = i * 4 + cg;
      lt[px * 257 + c] = xb[(size_t)c * HWS];
    }
  }
  __syncthreads();
  {
    const int slot = t & 31;             // 16B slot = 8 channels (32 slots/row)
    const int pxw  = t >> 5;             // 0..7
    unsigned char* xt = ws + XTOFF;
#pragma unroll
    for (int i = 0; i < 8; ++i) {
      const int p = i * 8 + pxw;
      const float* r = &lt[p * 257 + slot * 8];
      u32x4 v;
#pragma unroll
      for (int j = 0; j < 4; ++j)
        v[j] = (unsigned)f2bf(r[2 * j]) | ((unsigned)f2bf(r[2 * j + 1]) << 16);
      *(u32x4*)(xt + (size_t)(pg0 + p) * 512 + slot * 16) = v;
    }
  }
}

__global__ __launch_bounds__(256, 2) void conv_kernel(
    const unsigned char* __restrict__ ws, const float* __restrict__ bias,
    float* __restrict__ out) {
  // LDS: A bufs 0..3 at buf*8192; B bufs 0..3 at 32768 + buf*8192.
  __shared__ __align__(16) unsigned char smem[65536];

  const unsigned char* wb = ws;
  const unsigned char* xt = ws + XTOFF;
  const unsigned char* zp = ws + ZPOFF;

  const int bid = blockIdx.x;
  const int sw  = (bid & 7) * 196 + (bid >> 3);  // XCD-chunked, bijective (1568=8*196)
  const int co0 = (sw & 1) * 128;
  const int p0  = (sw >> 1) * 128;               // global pixel base

  const int t    = threadIdx.x;
  const int lane = t & 63;
  const int wave = t >> 6;     // 0..3
  const int wm   = wave & 1;   // co 64-half
  const int wn   = wave >> 1;  // px 64-half
  const int rl   = lane & 15;
  const int kq   = lane >> 4;
  const int q2   = lane >> 2;  // 0..15 (staging row within wave's 16)

  // staging: lane handles 16B chunk j of its row (pre-swizzled source)
  const unsigned jb = (unsigned)(((lane & 3) ^ ((lane >> 3) & 3)) * 16);

  const unsigned char* aG[2];
  long long bG[2];
  int hB[2], wB[2];
#pragma unroll
  for (int i = 0; i < 2; ++i) {
    const int row = i * 64 + wave * 16 + q2;      // 0..127
    aG[i] = wb + (size_t)(co0 + row) * WROWB + jb;
    const int pg = p0 + row;
    const int n  = pg / HWS;
    const int pi = pg - n * HWS;
    hB[i] = pi / 56;
    wB[i] = pi - hB[i] * 56;
    bG[i] = (long long)pg * 512 + (long long)jb;
  }

  f32x4 acc[4][4];
  const f32x4 zero4 = {0.f, 0.f, 0.f, 0.f};
#pragma unroll
  for (int mi = 0; mi < 4; ++mi)
#pragma unroll
    for (int ni = 0; ni < 4; ++ni) acc[mi][ni] = zero4;

  auto stage = [&](int s, int buf) {
    const int cq  = s / 9;
    const int tap = s - cq * 9;
    const int kh  = tap / 3;
    const int dh  = kh - 1;
    const int dw  = (tap - kh * 3) - 1;
    const unsigned koffA = (unsigned)(tap * 512 + cq * 64);
    unsigned char* lbA = smem + buf * 8192 + wave * 1024;
    unsigned char* lbB = smem + 32768 + buf * 8192 + wave * 1024;
#pragma unroll
    for (int i = 0; i < 2; ++i)
      __builtin_amdgcn_global_load_lds(
          (const GLOBAL_AS unsigned int*)(aG[i] + koffA),
          (LDS_AS unsigned int*)(lbA + i * 4096), 16, 0, 0);
    const long long doff = (long long)(dh * 56 + dw) * 512 + cq * 64;
#pragma unroll
    for (int i = 0; i < 2; ++i) {
      const int hh  = hB[i] + dh;
      const int wwi = wB[i] + dw;
      const bool ok = ((unsigned)hh < 56u) && ((unsigned)wwi < 56u);
      const unsigned char* g = ok ? (xt + bG[i] + doff) : zp;
      __builtin_amdgcn_global_load_lds(
          (const GLOBAL_AS unsigned int*)g,
          (LDS_AS unsigned int*)(lbB + i * 4096), 16, 0, 0);
    }
  };

  // compute-phase per-lane read offsets (64B rows, slot XOR (rl>>1)&3)
  const unsigned srd  = (unsigned)((kq ^ ((rl >> 1) & 3)) * 16);
  const unsigned offA = (unsigned)((wm * 64 + rl) * 64) + srd;
  const unsigned offB = (unsigned)((wn * 64 + rl) * 64) + srd;

#define STEP(S, BUF, VM, DO_STAGE)                                           \
  {                                                                          \
    asm volatile("s_waitcnt vmcnt(" VM ")\n\ts_barrier" ::: "memory");       \
    const unsigned char* bA = smem + (BUF) * 8192;                           \
    const unsigned char* bB = smem + 32768 + (BUF) * 8192;                   \
    short8 av[4], bv[4];                                                     \
    _Pragma("unroll") for (int mi = 0; mi < 4; ++mi)                         \
        av[mi] = *(const short8*)(bA + offA + mi * 1024);                    \
    _Pragma("unroll") for (int ni = 0; ni < 4; ++ni)                         \
        bv[ni] = *(const short8*)(bB + offB + ni * 1024);                    \
    if (DO_STAGE) stage((S) + 3, ((S) + 3) & 3);                             \
    __builtin_amdgcn_s_setprio(1);                                           \
    _Pragma("unroll") for (int mi = 0; mi < 4; ++mi)                         \
      _Pragma("unroll") for (int ni = 0; ni < 4; ++ni)                       \
          acc[mi][ni] = __builtin_amdgcn_mfma_f32_16x16x32_bf16(             \
              av[mi], bv[ni], acc[mi][ni], 0, 0, 0);                         \
    __builtin_amdgcn_s_setprio(0);                                           \
  }

  // ---- prologue: 3 stages in flight (12 outstanding DMA ops) ----
  stage(0, 0);
  stage(1, 1);
  stage(2, 2);

  // ---- main loop: 68 steps, counted vmcnt(8), stage s+3 each step ----
#pragma unroll 1
  for (int qq = 0; qq < 17; ++qq) {
    const int s = qq * 4;
    STEP(s + 0, 0, "8", true)
    STEP(s + 1, 1, "8", true)
    STEP(s + 2, 2, "8", true)
    STEP(s + 3, 3, "8", true)
  }
  // ---- tail: steps 68..71, drain 8 -> 4 -> 0 ----
  STEP(68, 0, "8", true)    // stages step 71
  STEP(69, 1, "8", false)
  STEP(70, 2, "4", false)
  STEP(71, 3, "0", false)
#undef STEP

  // ---- epilogue: bias + ReLU. C/D: col=lane&15, row=(lane>>4)*4+j ----
#pragma unroll
  for (int mi = 0; mi < 4; ++mi) {
    const int row = co0 + wm * 64 + mi * 16 + kq * 4;
    float br[4];
#pragma unroll
    for (int j = 0; j < 4; ++j) br[j] = bias[row + j];
#pragma unroll
    for (int ni = 0; ni < 4; ++ni) {
      const int pgb = p0 + wn * 64 + ni * 16;     // 16-span within one image
      const int n   = pgb / HWS;
      const int pib = pgb - n * HWS;
#pragma unroll
      for (int j = 0; j < 4; ++j) {
        float v = acc[mi][ni][j] + br[j];
        out[(size_t)(n * 256 + row + j) * HWS + pib + rl] = fmaxf(v, 0.f);
      }
    }
  }
}

// Correct-but-slow fallback if workspace is too small (not expected).
__global__ void naive_kernel(const float* __restrict__ x, const float* __restrict__ w,
                             const float* __restrict__ bias, float* __restrict__ out) {
  int idx = blockIdx.x * 256 + threadIdx.x;
  if (idx >= 32 * 256 * HWS) return;
  int n  = idx / (256 * HWS);
  int r  = idx - n * 256 * HWS;
  int co = r / HWS;
  int p  = r - co * HWS;
  int h = p / 56, ww = p - h * 56;
  float s = bias[co];
  const float* xb = x + (size_t)n * 256 * HWS;
  const float* wbp = w + (size_t)co * KTOT;
  for (int ci = 0; ci < 256; ++ci) {
    const float* xc = xb + (size_t)ci * HWS;
    const float* wc = wbp + ci * 9;
    for (int kh = 0; kh < 3; ++kh) {
      int hh = h + kh - 1;
      if ((unsigned)hh >= 56u) continue;
      for (int kw = 0; kw < 3; ++kw) {
        int w2 = ww + kw - 1;
        if ((unsigned)w2 >= 56u) continue;
        s += xc[hh * 56 + w2] * wc[kh * 3 + kw];
      }
    }
  }
  out[idx] = fmaxf(s, 0.f);
}

extern "C" void kernel_launch(void* const* d_in, const int* in_sizes, int n_in,
                              void* d_out, int out_size, void* d_ws, size_t ws_size,
                              hipStream_t stream) {
  const float* x    = (const float*)d_in[0];
  const float* w    = (const float*)d_in[1];
  const float* bias = (const float*)d_in[2];
  float* out        = (float*)d_out;

  if (ws_size < WSNEED) {
    hipLaunchKernelGGL(naive_kernel, dim3((32 * 256 * HWS + 255) / 256), dim3(256),
                       0, stream, x, w, bias, out);
    return;
  }
  unsigned char* ws = (unsigned char*)d_ws;
  hipLaunchKernelGGL(wcvt_kernel, dim3(2304), dim3(256), 0, stream, w, ws);
  hipLaunchKernelGGL(xcvt_kernel, dim3(PTOT / 64), dim3(256), 0, stream, x, ws);
  hipLaunchKernelGGL(conv_kernel, dim3(1568), dim3(256), 0, stream, ws, bias, out);
}